// Round 1
// baseline (302.987 us; speedup 1.0000x reference)
//
#include <hip/hip_runtime.h>

typedef __attribute__((ext_vector_type(8))) short short8;
typedef __attribute__((ext_vector_type(4))) float float4v;

#define HWDIM 128
#define NPIX_HID 8388608   // 8*64*128*128

__device__ __forceinline__ short f2bf(float f) {
    union { float f; unsigned u; } v; v.f = f;
    unsigned r = (v.u + 0x7FFFu + ((v.u >> 16) & 1u)) >> 16;
    return (short)r;
}

__device__ __forceinline__ float sigmoidf_(float v) { return 1.f / (1.f + __expf(-v)); }
__device__ __forceinline__ float tanhf_(float v)    { return 2.f / (1.f + __expf(-2.f * v)) - 1.f; }

// Pack W[co][ci][ky][kx] fp32 -> Aprep[kk][ci/8][co][ci%8] bf16 (MFMA A-frag order).
__global__ void wprep(const float* __restrict__ W, short* __restrict__ A) {
    int tid = blockIdx.x * 256 + threadIdx.x;
    if (tid >= 9 * 16 * 256 * 8) return;
    int j   = tid & 7;
    int co  = (tid >> 3) & 255;
    int cig = (tid >> 11) & 15;
    int kk  = tid >> 15;
    int ci  = cig * 8 + j;
    A[tid] = f2bf(W[co * 1152 + ci * 9 + kk]);
}

__global__ __launch_bounds__(256) void convlstm_main(
    const float* __restrict__ x, const float* __restrict__ ph,
    const float* __restrict__ pc, const short* __restrict__ aprep,
    const float* __restrict__ bg, float* __restrict__ out)
{
    __shared__ short Bs[64 * 40];   // [n=64][k=32 pad->40]  (row stride 80B: 2-way bank alias only)

    const int tid  = threadIdx.x;
    const int lane = tid & 63;
    const int wave = tid >> 6;
    const int l15  = lane & 15;
    const int quad = lane >> 4;
    const int kb   = wave * 8;      // this wave stages ci [kb, kb+8) of each 32-chunk

    const int t  = blockIdx.x;
    const int x0 = (t & 1) * 64;
    const int y  = (t >> 1) & 127;
    const int b  = t >> 8;

    float4v acc[4][4];
#pragma unroll
    for (int mt = 0; mt < 4; ++mt)
#pragma unroll
        for (int nt = 0; nt < 4; ++nt)
            acc[mt][nt] = (float4v){0.f, 0.f, 0.f, 0.f};

    for (int ky = 0; ky < 3; ++ky) {
        const int ysrc = y + ky - 1;
        const bool row_ok = (unsigned)ysrc < 128u;
        for (int kx = 0; kx < 3; ++kx) {
            const int kkk  = ky * 3 + kx;
            const int xsrc = x0 + kx - 1 + lane;          // n = lane
            const bool ok  = row_ok && ((unsigned)xsrc < 128u);
            for (int cc = 0; cc < 4; ++cc) {
                __syncthreads();   // previous chunk's reads complete
                // ---- stage B-tile: Bs[n][k] = bf16(stacked[b][cc*32+k][ysrc][xsrc]) ----
                short8 pk = {0, 0, 0, 0, 0, 0, 0, 0};
                if (ok) {
                    const float* src = (cc < 2) ? x : ph;
                    const int ci0 = (cc & 1) * 32 + kb;
                    const float* sp = src + (((b * 64 + ci0) * 128 + ysrc) * 128 + xsrc);
#pragma unroll
                    for (int j = 0; j < 8; ++j) pk[j] = f2bf(sp[j * 16384]);
                }
                *(short8*)&Bs[lane * 40 + kb] = pk;
                __syncthreads();

                // ---- fragments ----
                short8 afr[4], bfr[4];
                const int cig = cc * 4 + quad;            // k = cc*32 + quad*8 + j
                const short* abase = aprep + ((kkk * 16 + cig) * 256) * 8;
#pragma unroll
                for (int mt = 0; mt < 4; ++mt) {
                    const int co = mt * 64 + wave * 16 + l15;
                    afr[mt] = *(const short8*)(abase + co * 8);
                }
#pragma unroll
                for (int nt = 0; nt < 4; ++nt) {
                    const int n = nt * 16 + l15;
                    bfr[nt] = *(short8*)&Bs[n * 40 + quad * 8];
                }
#pragma unroll
                for (int mt = 0; mt < 4; ++mt)
#pragma unroll
                    for (int nt = 0; nt < 4; ++nt)
                        acc[mt][nt] = __builtin_amdgcn_mfma_f32_16x16x32_bf16(
                            afr[mt], bfr[nt], acc[mt][nt], 0, 0, 0);
            }
        }
    }

    // ---- fused gating epilogue (all 4 gates for channel c live in this lane) ----
#pragma unroll
    for (int nt = 0; nt < 4; ++nt) {
        const int px = x0 + nt * 16 + l15;
#pragma unroll
        for (int r = 0; r < 4; ++r) {
            const int c = wave * 16 + quad * 4 + r;
            const float gi = acc[0][nt][r] + bg[c];
            const float gf = acc[1][nt][r] + bg[64 + c];
            const float go = acc[2][nt][r] + bg[128 + c];
            const float gc = acc[3][nt][r] + bg[192 + c];
            const float ig = sigmoidf_(gi);
            const float fg = sigmoidf_(gf);
            const float og = sigmoidf_(go);
            const float cg = tanhf_(gc);
            const int idx = ((b * 64 + c) * 128 + y) * 128 + px;
            const float cell = ig * cg + fg * pc[idx];
            const float hid  = og * tanhf_(cell);
            out[idx] = hid;
            out[NPIX_HID + idx] = cell;
        }
    }
}

extern "C" void kernel_launch(void* const* d_in, const int* in_sizes, int n_in,
                              void* d_out, int out_size, void* d_ws, size_t ws_size,
                              hipStream_t stream) {
    const float* x  = (const float*)d_in[0];
    const float* ph = (const float*)d_in[1];
    const float* pc = (const float*)d_in[2];
    const float* W  = (const float*)d_in[3];
    const float* bg = (const float*)d_in[4];
    float* out = (float*)d_out;
    short* aprep = (short*)d_ws;   // 9*16*256*8 bf16 = 589,824 B

    wprep<<<1152, 256, 0, stream>>>(W, aprep);
    convlstm_main<<<2048, 256, 0, stream>>>(x, ph, pc, aprep, bg, out);
}

// Round 2
// 256.290 us; speedup vs baseline: 1.1822x; 1.1822x over previous
//
#include <hip/hip_runtime.h>

typedef __attribute__((ext_vector_type(8))) short short8;
typedef __attribute__((ext_vector_type(4))) short short4v;
typedef __attribute__((ext_vector_type(4))) float float4v;

#define NPIX_HID 8388608   // 8*64*128*128
#define PSTRIDE 132        // shorts per px row in LDS (264 B: dword stride 66 == 2 mod 32 -> 4-way max)

__device__ __forceinline__ short f2bf(float f) {
    union { float f; unsigned u; } v; v.f = f;
    unsigned r = (v.u + 0x7FFFu + ((v.u >> 16) & 1u)) >> 16;
    return (short)r;
}

__device__ __forceinline__ float sigmoidf_(float v) { return 1.f / (1.f + __expf(-v)); }
__device__ __forceinline__ float tanhf_(float v)    { return 2.f / (1.f + __expf(-2.f * v)) - 1.f; }

// Pack W[co][ci][ky][kx] fp32 -> Aprep[kk][ci/8][co][ci%8] bf16 (MFMA A-frag order).
__global__ void wprep(const float* __restrict__ W, short* __restrict__ A) {
    int tid = blockIdx.x * 256 + threadIdx.x;
    if (tid >= 9 * 16 * 256 * 8) return;
    int j   = tid & 7;
    int co  = (tid >> 3) & 255;
    int cig = (tid >> 11) & 15;
    int kk  = tid >> 15;
    int ci  = cig * 8 + j;
    A[tid] = f2bf(W[co * 1152 + ci * 9 + kk]);
}

__global__ __launch_bounds__(256, 3) void convlstm_main(
    const float* __restrict__ x, const float* __restrict__ ph,
    const float* __restrict__ pc, const short* __restrict__ aprep,
    const float* __restrict__ bg, float* __restrict__ out)
{
    // Bs[row 0..2][px 0..65][ci 0..127], px stride PSTRIDE shorts (pad 4)
    __shared__ short Bs[3 * 66 * PSTRIDE];   // 52272 B -> 3 blocks/CU

    const int tid  = threadIdx.x;
    const int lane = tid & 63;
    const int wave = tid >> 6;
    const int l15  = lane & 15;
    const int quad = lane >> 4;

    const int t  = blockIdx.x;
    const int x0 = (t & 1) * 64;
    const int y  = (t >> 1) & 127;
    const int b  = t >> 8;

    // ---- stage ALL input for this block: 3 halo rows x 66 px x 128 ci ----
    // flat i = (row*16 + oct)*66 + px  (consecutive tid -> consecutive px -> coalesced)
    for (int i = tid; i < 3168; i += 256) {
        const int px  = i % 66;
        const int ro  = i / 66;      // 0..47
        const int oct = ro & 15;     // ci octet
        const int row = ro >> 4;     // 0..2
        const int ysrc = y + row - 1;
        const int xsrc = x0 + px - 1;
        short4v lo = {0, 0, 0, 0}, hi = {0, 0, 0, 0};
        if ((unsigned)ysrc < 128u && (unsigned)xsrc < 128u) {
            const float* src = (oct < 8) ? x : ph;
            const float* sp = src + (((b * 64 + (oct & 7) * 8) * 128 + ysrc) * 128 + xsrc);
#pragma unroll
            for (int j = 0; j < 4; ++j) lo[j] = f2bf(sp[j * 16384]);
#pragma unroll
            for (int j = 0; j < 4; ++j) hi[j] = f2bf(sp[(j + 4) * 16384]);
        }
        short* dst = &Bs[(row * 66 + px) * PSTRIDE + oct * 8];
        *(short4v*)dst       = lo;
        *(short4v*)(dst + 4) = hi;
    }
    __syncthreads();

    // ---- all 9 taps x K=128 from LDS; A-frags from prepacked global (L2) ----
    float4v acc[4][4];
#pragma unroll
    for (int mt = 0; mt < 4; ++mt)
#pragma unroll
        for (int nt = 0; nt < 4; ++nt)
            acc[mt][nt] = (float4v){0.f, 0.f, 0.f, 0.f};

#pragma unroll
    for (int ky = 0; ky < 3; ++ky) {
#pragma unroll
        for (int kx = 0; kx < 3; ++kx) {
            const int kkk = ky * 3 + kx;
#pragma unroll
            for (int kc = 0; kc < 4; ++kc) {
                short8 afr[4], bfr[4];
                const short* ab = aprep + ((kkk * 16 + kc * 4 + quad) * 256) * 8;
#pragma unroll
                for (int mt = 0; mt < 4; ++mt)
                    afr[mt] = *(const short8*)(ab + (mt * 64 + wave * 16 + l15) * 8);
                const int bbase = (ky * 66 + kx + l15) * PSTRIDE + kc * 32 + quad * 8;
#pragma unroll
                for (int nt = 0; nt < 4; ++nt) {
                    const short* bp = &Bs[bbase + nt * 16 * PSTRIDE];
                    short4v blo = *(const short4v*)bp;
                    short4v bhi = *(const short4v*)(bp + 4);
                    short8 f;
                    f[0] = blo[0]; f[1] = blo[1]; f[2] = blo[2]; f[3] = blo[3];
                    f[4] = bhi[0]; f[5] = bhi[1]; f[6] = bhi[2]; f[7] = bhi[3];
                    bfr[nt] = f;
                }
#pragma unroll
                for (int mt = 0; mt < 4; ++mt)
#pragma unroll
                    for (int nt = 0; nt < 4; ++nt)
                        acc[mt][nt] = __builtin_amdgcn_mfma_f32_16x16x32_bf16(
                            afr[mt], bfr[nt], acc[mt][nt], 0, 0, 0);
            }
        }
    }

    // ---- fused gating epilogue (all 4 gates for channel c live in this lane) ----
#pragma unroll
    for (int nt = 0; nt < 4; ++nt) {
        const int px = x0 + nt * 16 + l15;
#pragma unroll
        for (int r = 0; r < 4; ++r) {
            const int c = wave * 16 + quad * 4 + r;
            const float gi = acc[0][nt][r] + bg[c];
            const float gf = acc[1][nt][r] + bg[64 + c];
            const float go = acc[2][nt][r] + bg[128 + c];
            const float gc = acc[3][nt][r] + bg[192 + c];
            const float ig = sigmoidf_(gi);
            const float fg = sigmoidf_(gf);
            const float og = sigmoidf_(go);
            const float cg = tanhf_(gc);
            const int idx = ((b * 64 + c) * 128 + y) * 128 + px;
            const float cell = ig * cg + fg * pc[idx];
            const float hid  = og * tanhf_(cell);
            out[idx] = hid;
            out[NPIX_HID + idx] = cell;
        }
    }
}

extern "C" void kernel_launch(void* const* d_in, const int* in_sizes, int n_in,
                              void* d_out, int out_size, void* d_ws, size_t ws_size,
                              hipStream_t stream) {
    const float* x  = (const float*)d_in[0];
    const float* ph = (const float*)d_in[1];
    const float* pc = (const float*)d_in[2];
    const float* W  = (const float*)d_in[3];
    const float* bg = (const float*)d_in[4];
    float* out = (float*)d_out;
    short* aprep = (short*)d_ws;   // 9*16*256*8 bf16 = 589,824 B

    wprep<<<1152, 256, 0, stream>>>(W, aprep);
    convlstm_main<<<2048, 256, 0, stream>>>(x, ph, pc, aprep, bg, out);
}

// Round 3
// 228.672 us; speedup vs baseline: 1.3250x; 1.1208x over previous
//
#include <hip/hip_runtime.h>

typedef __attribute__((ext_vector_type(8))) short short8;
typedef __attribute__((ext_vector_type(4))) float float4v;

#define NPIX_HID 8388608   // 8*64*128*128
#define PST 136            // shorts per px row in LDS: 272 B, 16B-aligned -> ds_read_b128, conflict-free

__device__ __forceinline__ short f2bf(float f) {
    union { float f; unsigned u; } v; v.f = f;
    unsigned r = (v.u + 0x7FFFu + ((v.u >> 16) & 1u)) >> 16;
    return (short)r;
}

__device__ __forceinline__ float sigmoidf_(float v) { return 1.f / (1.f + __expf(-v)); }
__device__ __forceinline__ float tanhf_(float v)    { return 2.f / (1.f + __expf(-2.f * v)) - 1.f; }

// Pack W[co][ci][ky][kx] fp32 -> Aprep[kk][ci/8][co][ci%8] bf16 (MFMA A-frag order).
__global__ void wprep(const float* __restrict__ W, short* __restrict__ A) {
    int tid = blockIdx.x * 256 + threadIdx.x;
    if (tid >= 9 * 16 * 256 * 8) return;
    int j   = tid & 7;
    int co  = (tid >> 3) & 255;
    int cig = (tid >> 11) & 15;
    int kk  = tid >> 15;
    int ci  = cig * 8 + j;
    A[tid] = f2bf(W[co * 1152 + ci * 9 + kk]);
}

__global__ __launch_bounds__(256, 2) void convlstm_main(
    const float* __restrict__ x, const float* __restrict__ ph,
    const float* __restrict__ pc, const short* __restrict__ aprep,
    const float* __restrict__ bg, float* __restrict__ out)
{
    // Bs[halo row 0..3][px 0..65][ci 0..127], px stride PST shorts -> 71808 B, 2 blocks/CU
    __shared__ short Bs[4 * 66 * PST];

    const int tid  = threadIdx.x;
    const int lane = tid & 63;
    const int wave = tid >> 6;
    const int l15  = lane & 15;
    const int quad = lane >> 4;

    const int t  = blockIdx.x;           // 1024 blocks: 2 x-halves, 64 row-pairs, 8 batch
    const int x0 = (t & 1) * 64;
    const int y0 = ((t >> 1) & 63) * 2;
    const int b  = t >> 7;

    // ---- stage 4 halo rows x 66 px x 128 ci, fp32->bf16 ----
    for (int i = tid; i < 4224; i += 256) {
        const int px  = i % 66;
        const int ro  = i / 66;      // 0..63
        const int oct = ro & 15;     // ci octet
        const int row = ro >> 4;     // 0..3 (ysrc = y0+row-1)
        const int ysrc = y0 + row - 1;
        const int xsrc = x0 + px - 1;
        short8 pk = {0,0,0,0,0,0,0,0};
        if ((unsigned)ysrc < 128u && (unsigned)xsrc < 128u) {
            const float* src = (oct < 8) ? x : ph;
            const float* sp = src + (((b * 64 + (oct & 7) * 8) * 128 + ysrc) * 128 + xsrc);
#pragma unroll
            for (int j = 0; j < 8; ++j) pk[j] = f2bf(sp[j * 16384]);
        }
        *(short8*)&Bs[(row * 66 + px) * PST + oct * 8] = pk;
    }
    __syncthreads();

    float4v acc[4][8];
#pragma unroll
    for (int mt = 0; mt < 4; ++mt)
#pragma unroll
        for (int nt = 0; nt < 8; ++nt)
            acc[mt][nt] = (float4v){0.f, 0.f, 0.f, 0.f};

    // ---- flat K-loop: kt = tap*4 + kc, A base linear in kt; prefetch A one iter ahead ----
    const int coff = (wave * 16 + l15) * 8;      // + mt*512 shorts
    short8 afr[4];
    {
        const short* ab = aprep + quad * 2048;
#pragma unroll
        for (int mt = 0; mt < 4; ++mt)
            afr[mt] = *(const short8*)(ab + mt * 512 + coff);
    }

#pragma unroll 1
    for (int kt = 0; kt < 36; ++kt) {
        const int ktn = (kt < 35) ? kt + 1 : 35;
        short8 anx[4];
        const short* abn = aprep + ktn * 8192 + quad * 2048;
#pragma unroll
        for (int mt = 0; mt < 4; ++mt)
            anx[mt] = *(const short8*)(abn + mt * 512 + coff);

        const int kkk = kt >> 2;
        const int kc  = kt & 3;
        const int ky  = (kkk * 11) >> 5;         // kkk/3 for 0..8
        const int kx  = kkk - ky * 3;
        const int kof = kc * 32 + quad * 8;

        short8 bfr[8];
#pragma unroll
        for (int nt = 0; nt < 8; ++nt) {
            const int rowh = ky + (nt >> 2);               // halo row 0..3
            const int pxi  = kx + ((nt & 3) << 4) + l15;   // 0..65
            bfr[nt] = *(const short8*)&Bs[(rowh * 66 + pxi) * PST + kof];
        }
#pragma unroll
        for (int mt = 0; mt < 4; ++mt)
#pragma unroll
            for (int nt = 0; nt < 8; ++nt)
                acc[mt][nt] = __builtin_amdgcn_mfma_f32_16x16x32_bf16(
                    afr[mt], bfr[nt], acc[mt][nt], 0, 0, 0);
#pragma unroll
        for (int mt = 0; mt < 4; ++mt) afr[mt] = anx[mt];
    }

    // ---- fused gating epilogue (all 4 gates for channel c live in this lane) ----
#pragma unroll
    for (int nt = 0; nt < 8; ++nt) {
        const int y  = y0 + (nt >> 2);
        const int px = x0 + ((nt & 3) << 4) + l15;
#pragma unroll
        for (int r = 0; r < 4; ++r) {
            const int c = wave * 16 + quad * 4 + r;
            const float gi = acc[0][nt][r] + bg[c];
            const float gf = acc[1][nt][r] + bg[64 + c];
            const float go = acc[2][nt][r] + bg[128 + c];
            const float gc = acc[3][nt][r] + bg[192 + c];
            const float ig = sigmoidf_(gi);
            const float fg = sigmoidf_(gf);
            const float og = sigmoidf_(go);
            const float cg = tanhf_(gc);
            const int idx = ((b * 64 + c) * 128 + y) * 128 + px;
            const float cell = ig * cg + fg * pc[idx];
            const float hid  = og * tanhf_(cell);
            out[idx] = hid;
            out[NPIX_HID + idx] = cell;
        }
    }
}

extern "C" void kernel_launch(void* const* d_in, const int* in_sizes, int n_in,
                              void* d_out, int out_size, void* d_ws, size_t ws_size,
                              hipStream_t stream) {
    const float* x  = (const float*)d_in[0];
    const float* ph = (const float*)d_in[1];
    const float* pc = (const float*)d_in[2];
    const float* W  = (const float*)d_in[3];
    const float* bg = (const float*)d_in[4];
    float* out = (float*)d_out;
    short* aprep = (short*)d_ws;   // 9*16*256*8 bf16 = 589,824 B

    wprep<<<1152, 256, 0, stream>>>(W, aprep);
    convlstm_main<<<1024, 256, 0, stream>>>(x, ph, pc, aprep, bg, out);
}

// Round 4
// 219.081 us; speedup vs baseline: 1.3830x; 1.0438x over previous
//
#include <hip/hip_runtime.h>

typedef __attribute__((ext_vector_type(8))) short short8;
typedef __attribute__((ext_vector_type(4))) short short4v;
typedef __attribute__((ext_vector_type(4))) float float4v;

#define NPIX_HID 8388608   // 8*64*128*128
#define PST 132            // shorts per px row in LDS (pitch 66 dwords: measured 0 conflicts w/ b64)

__device__ __forceinline__ short f2bf(float f) {
    union { float f; unsigned u; } v; v.f = f;
    unsigned r = (v.u + 0x7FFFu + ((v.u >> 16) & 1u)) >> 16;
    return (short)r;
}

__device__ __forceinline__ float sigmoidf_(float v) { return 1.f / (1.f + __expf(-v)); }
__device__ __forceinline__ float tanhf_(float v)    { return 2.f / (1.f + __expf(-2.f * v)) - 1.f; }

// Pack W[co][ci][ky][kx] fp32 -> Aprep[kk][ci/8][co][ci%8] bf16 (MFMA A-frag order).
__global__ void wprep(const float* __restrict__ W, short* __restrict__ A) {
    int tid = blockIdx.x * 256 + threadIdx.x;
    if (tid >= 9 * 16 * 256 * 8) return;
    int j   = tid & 7;
    int co  = (tid >> 3) & 255;
    int cig = (tid >> 11) & 15;
    int kk  = tid >> 15;
    int ci  = cig * 8 + j;
    A[tid] = f2bf(W[co * 1152 + ci * 9 + kk]);
}

__global__ __launch_bounds__(256, 2) void convlstm_main(
    const float* __restrict__ x, const float* __restrict__ ph,
    const float* __restrict__ pc, const short* __restrict__ aprep,
    const float* __restrict__ bg, float* __restrict__ out)
{
    // Bs[halo row 0..3][px 0..65][ci 0..127], px pitch PST shorts -> 69696 B, 2 blocks/CU
    __shared__ short Bs[4 * 66 * PST];

    const int tid  = threadIdx.x;
    const int lane = tid & 63;
    const int wave = tid >> 6;
    const int l15  = lane & 15;
    const int quad = lane >> 4;

    const int t  = blockIdx.x;           // 1024 blocks: 2 x-halves, 64 row-pairs, 8 batch
    const int x0 = (t & 1) * 64;
    const int y0 = ((t >> 1) & 63) * 2;
    const int b  = t >> 7;

    // ---- stage 4 halo rows x 66 px x 128 ci, fp32->bf16, b64 stores ----
    for (int i = tid; i < 4224; i += 256) {
        const int px  = i % 66;
        const int ro  = i / 66;      // 0..63
        const int oct = ro & 15;     // ci octet
        const int row = ro >> 4;     // 0..3 (ysrc = y0+row-1)
        const int ysrc = y0 + row - 1;
        const int xsrc = x0 + px - 1;
        short4v lo = {0,0,0,0}, hi = {0,0,0,0};
        if ((unsigned)ysrc < 128u && (unsigned)xsrc < 128u) {
            const float* src = (oct < 8) ? x : ph;
            const float* sp = src + (((b * 64 + (oct & 7) * 8) * 128 + ysrc) * 128 + xsrc);
#pragma unroll
            for (int j = 0; j < 4; ++j) lo[j] = f2bf(sp[j * 16384]);
#pragma unroll
            for (int j = 0; j < 4; ++j) hi[j] = f2bf(sp[(j + 4) * 16384]);
        }
        short* dst = &Bs[(row * 66 + px) * PST + oct * 8];
        *(short4v*)dst       = lo;
        *(short4v*)(dst + 4) = hi;
    }
    __syncthreads();

    float4v acc[4][8];
#pragma unroll
    for (int mt = 0; mt < 4; ++mt)
#pragma unroll
        for (int nt = 0; nt < 8; ++nt)
            acc[mt][nt] = (float4v){0.f, 0.f, 0.f, 0.f};

    // ---- K-loop: (ky,kx) unroll-1 with incremental bases; kc unrolled; all offsets immediate ----
    const short* ap = aprep + quad * 2048 + (wave * 16 + l15) * 8;   // + kt*8192 + mt*512
    short8 abuf[2][4];
#pragma unroll
    for (int mt = 0; mt < 4; ++mt) abuf[0][mt] = *(const short8*)(ap + mt * 512);

    const short* bb = &Bs[l15 * PST + quad * 8];

#pragma unroll 1
    for (int ky = 0; ky < 3; ++ky) {
#pragma unroll 1
        for (int kx = 0; kx < 3; ++kx) {
#pragma unroll
            for (int kc = 0; kc < 4; ++kc) {
                const int cur = kc & 1, nxt = cur ^ 1;
                const bool last = (ky == 2) & (kx == 2) & (kc == 3);
                const short* apn = last ? ap : (ap + 8192);
#pragma unroll
                for (int mt = 0; mt < 4; ++mt)
                    abuf[nxt][mt] = *(const short8*)(apn + mt * 512);
                ap = apn;

                short8 bfr[8];
#pragma unroll
                for (int nt = 0; nt < 8; ++nt) {
                    const short* bp = bb + (nt >> 2) * (66 * PST) + (nt & 3) * (16 * PST) + kc * 32;
                    short4v lo = *(const short4v*)bp;
                    short4v hi = *(const short4v*)(bp + 4);
                    bfr[nt] = __builtin_shufflevector(lo, hi, 0, 1, 2, 3, 4, 5, 6, 7);
                }
#pragma unroll
                for (int mt = 0; mt < 4; ++mt)
#pragma unroll
                    for (int nt = 0; nt < 8; ++nt)
                        acc[mt][nt] = __builtin_amdgcn_mfma_f32_16x16x32_bf16(
                            abuf[cur][mt], bfr[nt], acc[mt][nt], 0, 0, 0);
            }
            bb += PST;            // kx+1: px window shifts by 1
        }
        bb += 63 * PST;           // next ky: to (ky+1)*66 row base (we advanced 3 already)
    }

    // ---- fused gating epilogue (all 4 gates for channel c live in this lane) ----
#pragma unroll
    for (int nt = 0; nt < 8; ++nt) {
        const int y  = y0 + (nt >> 2);
        const int px = x0 + ((nt & 3) << 4) + l15;
#pragma unroll
        for (int r = 0; r < 4; ++r) {
            const int c = wave * 16 + quad * 4 + r;
            const float gi = acc[0][nt][r] + bg[c];
            const float gf = acc[1][nt][r] + bg[64 + c];
            const float go = acc[2][nt][r] + bg[128 + c];
            const float gc = acc[3][nt][r] + bg[192 + c];
            const float ig = sigmoidf_(gi);
            const float fg = sigmoidf_(gf);
            const float og = sigmoidf_(go);
            const float cg = tanhf_(gc);
            const int idx = ((b * 64 + c) * 128 + y) * 128 + px;
            const float cell = ig * cg + fg * pc[idx];
            const float hid  = og * tanhf_(cell);
            out[idx] = hid;
            out[NPIX_HID + idx] = cell;
        }
    }
}

extern "C" void kernel_launch(void* const* d_in, const int* in_sizes, int n_in,
                              void* d_out, int out_size, void* d_ws, size_t ws_size,
                              hipStream_t stream) {
    const float* x  = (const float*)d_in[0];
    const float* ph = (const float*)d_in[1];
    const float* pc = (const float*)d_in[2];
    const float* W  = (const float*)d_in[3];
    const float* bg = (const float*)d_in[4];
    float* out = (float*)d_out;
    short* aprep = (short*)d_ws;   // 9*16*256*8 bf16 = 589,824 B

    wprep<<<1152, 256, 0, stream>>>(W, aprep);
    convlstm_main<<<1024, 256, 0, stream>>>(x, ph, pc, aprep, bg, out);
}